// Round 10
// baseline (277.388 us; speedup 1.0000x reference)
//
#include <hip/hip_runtime.h>
#include <hip/hip_bf16.h>

typedef _Float16 h2_t  __attribute__((ext_vector_type(2)));
typedef _Float16 f16x8 __attribute__((ext_vector_type(8)));
typedef float    f32x4 __attribute__((ext_vector_type(4)));

__device__ __forceinline__ unsigned pack2(float lo, float hi) {
    union { h2_t h; unsigned u; } cv;
    cv.h.x = (_Float16)lo; cv.h.y = (_Float16)hi;
    return cv.u;
}

// ---------------------------------------------------------------------------
// Prep (merged): bid<9 -> w2 MFMA B-frags; bid>=9 -> whT transpose to f16.
// ---------------------------------------------------------------------------
__global__ __launch_bounds__(256) void k_prep(
    const float* __restrict__ w2, f16x8* __restrict__ w2f,
    const float* __restrict__ wh, _Float16* __restrict__ whT)
{
    int bid = blockIdx.x;
    if (bid < 9) {
        int idx = bid * 256 + threadIdx.x;      // 9*4*64 = 2304
        int lane = idx & 63;
        int nt   = (idx >> 6) & 3;
        int tap  = idx >> 8;
        int oc = nt * 16 + (lane & 15);
        int c0 = (lane >> 4) * 8;
        f16x8 v;
#pragma unroll
        for (int j = 0; j < 8; ++j)
            v[j] = (_Float16)w2[(tap * 32 + c0 + j) * 64 + oc];
        w2f[idx] = v;
    } else {
        int c = bid - 9;                        // 0..767
        int k = threadIdx.x;                    // 0..255
        whT[c * 256 + k] = (_Float16)wh[k * 768 + c];
    }
}

// ---------------------------------------------------------------------------
// Fused conv1(VALU) + conv2(MFMA) + global-average-pool.  1 block = 1 frame.
// ---------------------------------------------------------------------------
__global__ __launch_bounds__(512, 4) void k_conv(
    const float* __restrict__ x,    // [512][64][64][5]
    const float* __restrict__ w1,   // [3][3][5][32]
    const float* __restrict__ b1,   // [32]
    const f16x8* __restrict__ w2f,  // [9][4][64] B-frags
    const float* __restrict__ b2,   // [64]
    float* __restrict__ pooled)     // [512][64]
{
    __shared__ _Float16 c1s[32 * 33 * 32];   // [ih][iw(+pad)][c] 67.6 KB
    __shared__ float pl[8 * 64];

    const int n = blockIdx.x;
    const int tid = threadIdx.x;
    const int lane = tid & 63, wv = tid >> 6;

    {   // zero the iw==32 pad column
        int r = tid >> 4, d = tid & 15;
        ((unsigned*)c1s)[(r * 33 + 32) * 16 + d] = 0u;
    }

    const float* xf = x + (size_t)n * 20480;

    for (int pp = 0; pp < 2; ++pp) {
        int p = tid + pp * 512;
        int oh = p >> 5, ow = p & 31;
        float acc[32];
#pragma unroll
        for (int oc = 0; oc < 32; ++oc) acc[oc] = b1[oc];
#pragma unroll
        for (int ky = 0; ky < 3; ++ky) {
            int ih = 2 * oh + ky;
            if (ih < 64) {
                const float* rb = xf + (ih * 64 + 2 * ow) * 5;
                float xv[15];
                const float2* rb2 = (const float2*)rb;
#pragma unroll
                for (int q = 0; q < 5; ++q) {
                    float2 v = rb2[q];
                    xv[2 * q] = v.x; xv[2 * q + 1] = v.y;
                }
                if (ow < 31) {
                    float2 v5 = rb2[5], v6 = rb2[6];
                    xv[10] = v5.x; xv[11] = v5.y;
                    xv[12] = v6.x; xv[13] = v6.y;
                    xv[14] = rb[14];
                } else {
                    xv[10] = xv[11] = xv[12] = xv[13] = xv[14] = 0.f;
                }
#pragma unroll
                for (int q = 0; q < 15; ++q) {
                    float v = xv[q];
                    const float* wp = w1 + (ky * 15 + q) * 32;
#pragma unroll
                    for (int oc = 0; oc < 32; ++oc)
                        acc[oc] = fmaf(v, wp[oc], acc[oc]);
                }
            }
        }
        unsigned* dst = (unsigned*)&c1s[(oh * 33 + ow) * 32];
#pragma unroll
        for (int j = 0; j < 16; ++j)
            dst[j] = pack2(fmaxf(acc[2 * j], 0.f), fmaxf(acc[2 * j + 1], 0.f));
    }
    __syncthreads();

    // conv2 as implicit GEMM via MFMA: M=256 px, N=64 oc, K=9x32
    f32x4 acc2[2][4];
#pragma unroll
    for (int mt = 0; mt < 2; ++mt)
#pragma unroll
        for (int nt = 0; nt < 4; ++nt) acc2[mt][nt] = f32x4{0.f, 0.f, 0.f, 0.f};

    const int owl = lane & 15;
    const int cb = (lane >> 4) * 8;
#pragma unroll
    for (int tap = 0; tap < 9; ++tap) {
        const int ky = tap / 3, kx = tap % 3;
        f16x8 bf[4];
#pragma unroll
        for (int nt = 0; nt < 4; ++nt)
            bf[nt] = w2f[(tap * 4 + nt) * 64 + lane];
#pragma unroll
        for (int mt = 0; mt < 2; ++mt) {
            int oh2 = wv + mt * 8;
            int ih = 2 * oh2 + ky;
            if (ih < 32) {
                int iw = 2 * owl + kx;
                f16x8 af = *(const f16x8*)&c1s[(ih * 33 + iw) * 32 + cb];
#pragma unroll
                for (int nt = 0; nt < 4; ++nt)
                    acc2[mt][nt] = __builtin_amdgcn_mfma_f32_16x16x32_f16(
                        af, bf[nt], acc2[mt][nt], 0, 0, 0);
            }
        }
    }

#pragma unroll
    for (int nt = 0; nt < 4; ++nt) {
        float b = b2[nt * 16 + owl];
        float s = 0.f;
#pragma unroll
        for (int mt = 0; mt < 2; ++mt)
#pragma unroll
            for (int r = 0; r < 4; ++r)
                s += fmaxf(acc2[mt][nt][r] + b, 0.f);
        s += __shfl_xor(s, 16, 64);
        s += __shfl_xor(s, 32, 64);
        if (lane < 16) pl[wv * 64 + nt * 16 + lane] = s;
    }
    __syncthreads();
    if (tid < 64) {
        float s = 0.f;
#pragma unroll
        for (int w = 0; w < 8; ++w) s += pl[w * 64 + tid];
        pooled[n * 64 + tid] = s * (1.0f / 256.0f);
    }
}

// ---------------------------------------------------------------------------
// Dense: feats = relu(pooled @ dw + db);  xg = feats @ wx + b_gru.
// ---------------------------------------------------------------------------
__global__ __launch_bounds__(256) void k_dense(
    const float* __restrict__ pooled,  // [512][64]
    const float* __restrict__ dw,      // [64][256]
    const float* __restrict__ db,      // [256]
    const float* __restrict__ wx,      // [256][768]
    const float* __restrict__ bg,      // [768]
    float* __restrict__ xg)            // [512][768]
{
    __shared__ float ps[4 * 64];
    __shared__ float fs[4 * 256];
    const int tid = threadIdx.x;
    const int r0 = blockIdx.x * 4;

    ps[tid & 255] = pooled[r0 * 64 + (tid & 255)];
    __syncthreads();

    {
        float a0 = db[tid], a1 = a0, a2 = a0, a3 = a0;
        for (int k = 0; k < 64; ++k) {
            float w = dw[k * 256 + tid];
            a0 = fmaf(ps[0 * 64 + k], w, a0);
            a1 = fmaf(ps[1 * 64 + k], w, a1);
            a2 = fmaf(ps[2 * 64 + k], w, a2);
            a3 = fmaf(ps[3 * 64 + k], w, a3);
        }
        fs[0 * 256 + tid] = fmaxf(a0, 0.f);
        fs[1 * 256 + tid] = fmaxf(a1, 0.f);
        fs[2 * 256 + tid] = fmaxf(a2, 0.f);
        fs[3 * 256 + tid] = fmaxf(a3, 0.f);
    }
    __syncthreads();

    float acc[3][4];
#pragma unroll
    for (int g = 0; g < 3; ++g) {
        float b = bg[g * 256 + tid];
#pragma unroll
        for (int r = 0; r < 4; ++r) acc[g][r] = b;
    }
    for (int k = 0; k < 256; ++k) {
        float f0 = fs[0 * 256 + k], f1 = fs[1 * 256 + k];
        float f2 = fs[2 * 256 + k], f3 = fs[3 * 256 + k];
#pragma unroll
        for (int g = 0; g < 3; ++g) {
            float w = wx[k * 768 + g * 256 + tid];
            acc[g][0] = fmaf(f0, w, acc[g][0]);
            acc[g][1] = fmaf(f1, w, acc[g][1]);
            acc[g][2] = fmaf(f2, w, acc[g][2]);
            acc[g][3] = fmaf(f3, w, acc[g][3]);
        }
    }
#pragma unroll
    for (int r = 0; r < 4; ++r)
#pragma unroll
        for (int g = 0; g < 3; ++g)
            xg[(size_t)(r0 + r) * 768 + g * 256 + tid] = acc[g][r];
}

// ---------------------------------------------------------------------------
// GRU scan as per-step GEMM: H[16,256] @ wh[256,768] via MFMA builtins.
// ONE block, 512 thr, 8 waves.  B-fragments are plain statically-indexed
// locals (192 regs/thread); __launch_bounds__(512,1) gives the allocator the
// full unified budget (512/wave; 8 waves over 4 SIMDs = 2/SIMD fits the
// 2048-reg file), and CDNA regalloc spills VGPR overflow to AGPRs (same
// file, cheap) rather than scratch.  No inline asm: compiler owns hazards
// (R9's raw-asm MFMA faulted).  Fragment layouts identical to the
// HW-verified conv2 implicit GEMM (R2+):
//   A: row=l&15, k=kt*32+(l>>4)*8+j;  B: col=nt*16+(l&15), same k;
//   C: col=l&15, row=(l>>4)*4+reg.
// Wave wv: phase1 cols [wv*64, wv*64+64) of z|r; phase2 cols 512+[wv*32,+32).
// ---------------------------------------------------------------------------
__global__ __launch_bounds__(512, 1) void k_gru(
    const _Float16* __restrict__ whT,  // [768 cols][256 k] f16
    const float* __restrict__ xg,      // [512][768]  (b*32+t major)
    float* __restrict__ out)           // [16*32*256] seq ++ [16*256] state
{
    __shared__ _Float16 hh[16 * 264];   // h(t) f16, row pad +8
    __shared__ _Float16 rhh[16 * 264];  // r*h f16, row pad +8
    __shared__ float    hf[16 * 256];   // h(t) f32
    __shared__ float    gs[16 * 512];   // sigmoid gates z|r

    const int tid = threadIdx.x;
    const int lane = tid & 63, wv = tid >> 6;
    const int ln15 = lane & 15;
    const int kb   = (lane >> 4) * 8;
    const int row0 = (lane >> 4) * 4;

    // ---- B-fragments, loaded once (statically indexed -> registers) ----
    f16x8 B1[4][8];     // [ntile][ktile], z|r cols
    f16x8 B2[2][8];     // hc cols
#pragma unroll
    for (int nt = 0; nt < 4; ++nt) {
        const _Float16* P = whT + (size_t)(wv * 64 + nt * 16 + ln15) * 256 + kb;
#pragma unroll
        for (int kt = 0; kt < 8; ++kt)
            B1[nt][kt] = *(const f16x8*)(P + kt * 32);
    }
#pragma unroll
    for (int nt = 0; nt < 2; ++nt) {
        const _Float16* P = whT + (size_t)(512 + wv * 32 + nt * 16 + ln15) * 256 + kb;
#pragma unroll
        for (int kt = 0; kt < 8; ++kt)
            B2[nt][kt] = *(const f16x8*)(P + kt * 32);
    }

    for (int i = tid; i < 16 * 256; i += 512) hf[i] = 0.f;
    for (int i = tid; i < 16 * 264; i += 512) {
        hh[i] = (_Float16)0.f; rhh[i] = (_Float16)0.f;
    }
    __syncthreads();

    const _Float16* hA = hh + ln15 * 264 + kb;
    const _Float16* rA = rhh + ln15 * 264 + kb;

    for (int t = 0; t < 32; ++t) {
        // ---- phase1 x preload (z|r cols; global loads hide under MFMA) ----
        float xv[4][4];
#pragma unroll
        for (int q = 0; q < 4; ++q)
#pragma unroll
            for (int r = 0; r < 4; ++r)
                xv[q][r] = xg[(size_t)((row0 + r) * 32 + t) * 768 +
                              wv * 64 + q * 16 + ln15];

        // ---- phase1 MFMAs: z|r pre-activations for this wave's 64 cols ----
        f32x4 ac[4];
#pragma unroll
        for (int nt = 0; nt < 4; ++nt) ac[nt] = f32x4{0.f, 0.f, 0.f, 0.f};
#pragma unroll
        for (int kt = 0; kt < 8; ++kt) {
            f16x8 af = *(const f16x8*)(hA + kt * 32);
#pragma unroll
            for (int nt = 0; nt < 4; ++nt)
                ac[nt] = __builtin_amdgcn_mfma_f32_16x16x32_f16(
                    af, B1[nt][kt], ac[nt], 0, 0, 0);
        }

        // ---- sigmoid + gs writes (concat cols 0..511 = z|r) ----
#pragma unroll
        for (int q = 0; q < 4; ++q)
#pragma unroll
            for (int r = 0; r < 4; ++r) {
                float v = ac[q][r] + xv[q][r];
                float g = 1.f / (1.f + __expf(-v));
                gs[(row0 + r) * 512 + wv * 64 + q * 16 + ln15] = g;
            }
        __syncthreads();                         // B1: gs ready

        // ---- rhh = r * h  (f16) ----
        {
            int rr = tid >> 5;                   // 0..15
            int cb8 = (tid & 31) * 8;            // 0..248
            f16x8 rw_;
#pragma unroll
            for (int j = 0; j < 8; ++j) {
                float rg = gs[rr * 512 + 256 + cb8 + j];
                float h0 = hf[rr * 256 + cb8 + j];
                rw_[j] = (_Float16)(rg * h0);
            }
            *(f16x8*)&rhh[rr * 264 + cb8] = rw_;
        }
        __syncthreads();                         // B2: rhh ready

        // ---- phase2 x preload (hc cols) ----
        float xv2[2][4];
#pragma unroll
        for (int q = 0; q < 2; ++q)
#pragma unroll
            for (int r = 0; r < 4; ++r)
                xv2[q][r] = xg[(size_t)((row0 + r) * 32 + t) * 768 + 512 +
                               wv * 32 + q * 16 + ln15];

        // ---- phase2 MFMAs: candidate pre-activations (32 cols/wave) ----
        f32x4 bc[2];
#pragma unroll
        for (int nt = 0; nt < 2; ++nt) bc[nt] = f32x4{0.f, 0.f, 0.f, 0.f};
#pragma unroll
        for (int kt = 0; kt < 8; ++kt) {
            f16x8 af = *(const f16x8*)(rA + kt * 32);
#pragma unroll
            for (int nt = 0; nt < 2; ++nt)
                bc[nt] = __builtin_amdgcn_mfma_f32_16x16x32_f16(
                    af, B2[nt][kt], bc[nt], 0, 0, 0);
        }

        // ---- tanh + h update + outputs ----
#pragma unroll
        for (int q = 0; q < 2; ++q)
#pragma unroll
            for (int r = 0; r < 4; ++r) {
                int row = row0 + r;
                int c2 = wv * 32 + q * 16 + ln15;
                float v = bc[q][r] + xv2[q][r];
                v = fminf(fmaxf(v, -15.f), 15.f);
                float e2 = __expf(2.f * v);
                float hc = (e2 - 1.f) / (e2 + 1.f);
                float z  = gs[row * 512 + c2];
                float h0 = hf[row * 256 + c2];
                float hn = z * h0 + (1.f - z) * hc;
                hf[row * 256 + c2] = hn;
                hh[row * 264 + c2] = (_Float16)hn;
                out[row * 8192 + t * 256 + c2] = hn;
                if (t == 31) out[131072 + row * 256 + c2] = hn;
            }
        __syncthreads();                         // B3: h(t) visible
    }
}

// ---------------------------------------------------------------------------
extern "C" void kernel_launch(void* const* d_in, const int* in_sizes, int n_in,
                              void* d_out, int out_size, void* d_ws,
                              size_t ws_size, hipStream_t stream)
{
    const float* x  = (const float*)d_in[0];
    const float* w1 = (const float*)d_in[1];
    const float* b1 = (const float*)d_in[2];
    const float* w2 = (const float*)d_in[3];
    const float* b2 = (const float*)d_in[4];
    const float* dw = (const float*)d_in[5];
    const float* db = (const float*)d_in[6];
    const float* wx = (const float*)d_in[7];
    const float* wh = (const float*)d_in[8];
    const float* bg = (const float*)d_in[9];
    float* out = (float*)d_out;

    float* pooled = (float*)d_ws;                  // 512*64 f32
    float* xg = pooled + 512 * 64;                 // 512*768 f32
    f16x8* w2f = (f16x8*)(xg + 512 * 768);         // 9*4*64 f16x8 (36.9 KB)
    _Float16* whT = (_Float16*)(w2f + 9 * 4 * 64); // 768*256 f16 (384 KB)

    k_prep<<<777, 256, 0, stream>>>(w2, w2f, wh, whT);
    k_conv<<<512, 512, 0, stream>>>(x, w1, b1, w2f, b2, pooled);
    k_dense<<<128, 256, 0, stream>>>(pooled, dw, db, wx, bg, xg);
    k_gru<<<1, 512, 0, stream>>>(whT, xg, out);
}

// Round 12
// 148.425 us; speedup vs baseline: 1.8689x; 1.8689x over previous
//
#include <hip/hip_runtime.h>
#include <hip/hip_bf16.h>

typedef _Float16 h2_t  __attribute__((ext_vector_type(2)));
typedef _Float16 f16x8 __attribute__((ext_vector_type(8)));
typedef float    f32x4 __attribute__((ext_vector_type(4)));

__device__ __forceinline__ float fdot2(h2_t a, h2_t b, float c) {
#if __has_builtin(__builtin_amdgcn_fdot2)
    return __builtin_amdgcn_fdot2(a, b, c, false);
#else
    return c + (float)a.x * (float)b.x + (float)a.y * (float)b.y;
#endif
}

__device__ __forceinline__ unsigned pack2(float lo, float hi) {
    union { h2_t h; unsigned u; } cv;
    cv.h.x = (_Float16)lo; cv.h.y = (_Float16)hi;
    return cv.u;
}

// ---------------------------------------------------------------------------
// Prep (merged): bid<9 -> w2 MFMA B-frags; bid>=9 -> whT transpose to f16.
// ---------------------------------------------------------------------------
__global__ __launch_bounds__(256) void k_prep(
    const float* __restrict__ w2, f16x8* __restrict__ w2f,
    const float* __restrict__ wh, _Float16* __restrict__ whT)
{
    int bid = blockIdx.x;
    if (bid < 9) {
        int idx = bid * 256 + threadIdx.x;      // 9*4*64 = 2304
        int lane = idx & 63;
        int nt   = (idx >> 6) & 3;
        int tap  = idx >> 8;
        int oc = nt * 16 + (lane & 15);
        int c0 = (lane >> 4) * 8;
        f16x8 v;
#pragma unroll
        for (int j = 0; j < 8; ++j)
            v[j] = (_Float16)w2[(tap * 32 + c0 + j) * 64 + oc];
        w2f[idx] = v;
    } else {
        int c = bid - 9;                        // 0..767
        int k = threadIdx.x;                    // 0..255
        whT[c * 256 + k] = (_Float16)wh[k * 768 + c];
    }
}

// ---------------------------------------------------------------------------
// Fused conv1(VALU) + conv2(MFMA) + global-average-pool.  1 block = 1 frame.
// ---------------------------------------------------------------------------
__global__ __launch_bounds__(512, 4) void k_conv(
    const float* __restrict__ x,    // [512][64][64][5]
    const float* __restrict__ w1,   // [3][3][5][32]
    const float* __restrict__ b1,   // [32]
    const f16x8* __restrict__ w2f,  // [9][4][64] B-frags
    const float* __restrict__ b2,   // [64]
    float* __restrict__ pooled)     // [512][64]
{
    __shared__ _Float16 c1s[32 * 33 * 32];   // [ih][iw(+pad)][c] 67.6 KB
    __shared__ float pl[8 * 64];

    const int n = blockIdx.x;
    const int tid = threadIdx.x;
    const int lane = tid & 63, wv = tid >> 6;

    {   // zero the iw==32 pad column
        int r = tid >> 4, d = tid & 15;
        ((unsigned*)c1s)[(r * 33 + 32) * 16 + d] = 0u;
    }

    const float* xf = x + (size_t)n * 20480;

    for (int pp = 0; pp < 2; ++pp) {
        int p = tid + pp * 512;
        int oh = p >> 5, ow = p & 31;
        float acc[32];
#pragma unroll
        for (int oc = 0; oc < 32; ++oc) acc[oc] = b1[oc];
#pragma unroll
        for (int ky = 0; ky < 3; ++ky) {
            int ih = 2 * oh + ky;
            if (ih < 64) {
                const float* rb = xf + (ih * 64 + 2 * ow) * 5;
                float xv[15];
                const float2* rb2 = (const float2*)rb;
#pragma unroll
                for (int q = 0; q < 5; ++q) {
                    float2 v = rb2[q];
                    xv[2 * q] = v.x; xv[2 * q + 1] = v.y;
                }
                if (ow < 31) {
                    float2 v5 = rb2[5], v6 = rb2[6];
                    xv[10] = v5.x; xv[11] = v5.y;
                    xv[12] = v6.x; xv[13] = v6.y;
                    xv[14] = rb[14];
                } else {
                    xv[10] = xv[11] = xv[12] = xv[13] = xv[14] = 0.f;
                }
#pragma unroll
                for (int q = 0; q < 15; ++q) {
                    float v = xv[q];
                    const float* wp = w1 + (ky * 15 + q) * 32;
#pragma unroll
                    for (int oc = 0; oc < 32; ++oc)
                        acc[oc] = fmaf(v, wp[oc], acc[oc]);
                }
            }
        }
        unsigned* dst = (unsigned*)&c1s[(oh * 33 + ow) * 32];
#pragma unroll
        for (int j = 0; j < 16; ++j)
            dst[j] = pack2(fmaxf(acc[2 * j], 0.f), fmaxf(acc[2 * j + 1], 0.f));
    }
    __syncthreads();

    // conv2 as implicit GEMM via MFMA: M=256 px, N=64 oc, K=9x32
    f32x4 acc2[2][4];
#pragma unroll
    for (int mt = 0; mt < 2; ++mt)
#pragma unroll
        for (int nt = 0; nt < 4; ++nt) acc2[mt][nt] = f32x4{0.f, 0.f, 0.f, 0.f};

    const int owl = lane & 15;
    const int cb = (lane >> 4) * 8;
#pragma unroll
    for (int tap = 0; tap < 9; ++tap) {
        const int ky = tap / 3, kx = tap % 3;
        f16x8 bf[4];
#pragma unroll
        for (int nt = 0; nt < 4; ++nt)
            bf[nt] = w2f[(tap * 4 + nt) * 64 + lane];
#pragma unroll
        for (int mt = 0; mt < 2; ++mt) {
            int oh2 = wv + mt * 8;
            int ih = 2 * oh2 + ky;
            if (ih < 32) {
                int iw = 2 * owl + kx;
                f16x8 af = *(const f16x8*)&c1s[(ih * 33 + iw) * 32 + cb];
#pragma unroll
                for (int nt = 0; nt < 4; ++nt)
                    acc2[mt][nt] = __builtin_amdgcn_mfma_f32_16x16x32_f16(
                        af, bf[nt], acc2[mt][nt], 0, 0, 0);
            }
        }
    }

#pragma unroll
    for (int nt = 0; nt < 4; ++nt) {
        float b = b2[nt * 16 + owl];
        float s = 0.f;
#pragma unroll
        for (int mt = 0; mt < 2; ++mt)
#pragma unroll
            for (int r = 0; r < 4; ++r)
                s += fmaxf(acc2[mt][nt][r] + b, 0.f);
        s += __shfl_xor(s, 16, 64);
        s += __shfl_xor(s, 32, 64);
        if (lane < 16) pl[wv * 64 + nt * 16 + lane] = s;
    }
    __syncthreads();
    if (tid < 64) {
        float s = 0.f;
#pragma unroll
        for (int w = 0; w < 8; ++w) s += pl[w * 64 + tid];
        pooled[n * 64 + tid] = s * (1.0f / 256.0f);
    }
}

// ---------------------------------------------------------------------------
// Dense: feats = relu(pooled @ dw + db);  xg = feats @ wx + b_gru.
// ---------------------------------------------------------------------------
__global__ __launch_bounds__(256) void k_dense(
    const float* __restrict__ pooled,  // [512][64]
    const float* __restrict__ dw,      // [64][256]
    const float* __restrict__ db,      // [256]
    const float* __restrict__ wx,      // [256][768]
    const float* __restrict__ bg,      // [768]
    float* __restrict__ xg)            // [512][768]
{
    __shared__ float ps[4 * 64];
    __shared__ float fs[4 * 256];
    const int tid = threadIdx.x;
    const int r0 = blockIdx.x * 4;

    ps[tid & 255] = pooled[r0 * 64 + (tid & 255)];
    __syncthreads();

    {
        float a0 = db[tid], a1 = a0, a2 = a0, a3 = a0;
        for (int k = 0; k < 64; ++k) {
            float w = dw[k * 256 + tid];
            a0 = fmaf(ps[0 * 64 + k], w, a0);
            a1 = fmaf(ps[1 * 64 + k], w, a1);
            a2 = fmaf(ps[2 * 64 + k], w, a2);
            a3 = fmaf(ps[3 * 64 + k], w, a3);
        }
        fs[0 * 256 + tid] = fmaxf(a0, 0.f);
        fs[1 * 256 + tid] = fmaxf(a1, 0.f);
        fs[2 * 256 + tid] = fmaxf(a2, 0.f);
        fs[3 * 256 + tid] = fmaxf(a3, 0.f);
    }
    __syncthreads();

    float acc[3][4];
#pragma unroll
    for (int g = 0; g < 3; ++g) {
        float b = bg[g * 256 + tid];
#pragma unroll
        for (int r = 0; r < 4; ++r) acc[g][r] = b;
    }
    for (int k = 0; k < 256; ++k) {
        float f0 = fs[0 * 256 + k], f1 = fs[1 * 256 + k];
        float f2 = fs[2 * 256 + k], f3 = fs[3 * 256 + k];
#pragma unroll
        for (int g = 0; g < 3; ++g) {
            float w = wx[k * 768 + g * 256 + tid];
            acc[g][0] = fmaf(f0, w, acc[g][0]);
            acc[g][1] = fmaf(f1, w, acc[g][1]);
            acc[g][2] = fmaf(f2, w, acc[g][2]);
            acc[g][3] = fmaf(f3, w, acc[g][3]);
        }
    }
#pragma unroll
    for (int r = 0; r < 4; ++r)
#pragma unroll
        for (int g = 0; g < 3; ++g)
            xg[(size_t)(r0 + r) * 768 + g * 256 + tid] = acc[g][r];
}

// ---------------------------------------------------------------------------
// GRU scan.  Weight residency (final form, from the R2-R11 laws):
//   wz -> AGPRs a0..a63   (R7-proven accvgpr write/read mechanics)
//   wr -> AGPRs a64..a127
//   wc -> LDS, padded 264 elem/col (528 B): bank-quad = (col+J) mod 8,
//         perfectly uniform -> conflict-free b128 reads.  No XOR swizzle.
// Arch VGPR demand = working set only (~50) -> no compiler spills -> no
// spill-to-AGPR collision (R11's failure mode).  Every ARD also clobbers
// its AGPR so the compiler can never park values in a0..a127.
// 116ish arch + 128 agpr ~= 244/wave -> 2 waves/SIMD (R7 was 1).
// 16 blocks x 512 thr; col = wv*32+(lane&31); kc = lane>>5 (k-half).
// ---------------------------------------------------------------------------
union H2I { h2_t h; int i; };

#define SV2(v, i) __builtin_shufflevector((v), (v), 2*(i), 2*(i)+1)

#define AWR(N, val) asm volatile("v_accvgpr_write_b32 a" #N ", %0" \
                                 :: "v"(val) : "a" #N)
#define ARD(N, dst) asm volatile("v_accvgpr_read_b32 %0, a" #N \
                                 : "=v"(dst) : : "a" #N)

#define AG4(P, BOFF, N0, N1, N2, N3) do {                               \
    union { f16x8 v; int i[4]; } u_;                                    \
    u_.v = *(const f16x8*)((P) + (BOFF));                               \
    AWR(N0, u_.i[0]); AWR(N1, u_.i[1]);                                 \
    AWR(N2, u_.i[2]); AWR(N3, u_.i[3]);                                 \
} while (0)

// phase1: z-dots from a(Z0..Z3), r-dots from a(R0..R3)
#define ZR(J, Z0, Z1, Z2, Z3, R0, R1, R2, R3) do {                      \
    f16x8 hv_ = hh8[kc * 16 + J];                                       \
    h2_t h0_ = SV2(hv_, 0), h1_ = SV2(hv_, 1);                          \
    h2_t h2_ = SV2(hv_, 2), h3_ = SV2(hv_, 3);                          \
    H2I z0_, z1_, z2_, z3_, r0_, r1_, r2_, r3_;                         \
    ARD(Z0, z0_.i); ARD(Z1, z1_.i); ARD(Z2, z2_.i); ARD(Z3, z3_.i);     \
    ARD(R0, r0_.i); ARD(R1, r1_.i); ARD(R2, r2_.i); ARD(R3, r3_.i);     \
    az0 = fdot2(z0_.h, h0_, az0); az1 = fdot2(z1_.h, h1_, az1);         \
    az0 = fdot2(z2_.h, h2_, az0); az1 = fdot2(z3_.h, h3_, az1);         \
    ar0 = fdot2(r0_.h, h0_, ar0); ar1 = fdot2(r1_.h, h1_, ar1);         \
    ar0 = fdot2(r2_.h, h2_, ar0); ar1 = fdot2(r3_.h, h3_, ar1);         \
} while (0)

// phase2: c-dots from padded LDS (conflict-free)
#define CC(J) do {                                                      \
    f16x8 rv_ = rh8[kc * 16 + J];                                       \
    f16x8 wc_ = *(const f16x8*)(wcb + (J) * 8);                         \
    ah0 = fdot2(SV2(wc_, 0), SV2(rv_, 0), ah0);                         \
    ah1 = fdot2(SV2(wc_, 1), SV2(rv_, 1), ah1);                         \
    ah0 = fdot2(SV2(wc_, 2), SV2(rv_, 2), ah0);                         \
    ah1 = fdot2(SV2(wc_, 3), SV2(rv_, 3), ah1);                         \
} while (0)

__global__ __launch_bounds__(512) void k_gru(
    const _Float16* __restrict__ whT,  // [768 cols][256 k] f16
    const float* __restrict__ xg,      // [512][768]
    float* __restrict__ out)           // [16*32*256] seq ++ [16*256] state
{
    __shared__ _Float16 wcs[256 * 264];  // candidate weights, padded, 132 KB
    __shared__ float hf[256];
    __shared__ _Float16 hh[256];
    __shared__ _Float16 rhh[256];

    const int b = blockIdx.x;
    const int tid = threadIdx.x;
    const int lane = tid & 63, wv = tid >> 6;
    const int col = wv * 32 + (lane & 31);
    const int kc = lane >> 5;          // 0 or 1
    const int k0 = kc * 128;

    // ---- wc -> LDS, linear chunks, 264-elem column stride ----
    for (int i = tid; i < 256 * 32; i += 512) {
        int c  = i >> 5;               // col 0..255
        int cj = i & 31;               // 16B chunk
        *(f16x8*)&wcs[c * 264 + cj * 8] =
            *(const f16x8*)(whT + (size_t)(512 + c) * 256 + cj * 8);
    }

    // ---- wz -> a0..a63, wr -> a64..a127 ----
    {
        const _Float16* pz = whT + (size_t)col * 256 + k0;
        AG4(pz,   0,  0,  1,  2,  3); AG4(pz,   8,  4,  5,  6,  7);
        AG4(pz,  16,  8,  9, 10, 11); AG4(pz,  24, 12, 13, 14, 15);
        AG4(pz,  32, 16, 17, 18, 19); AG4(pz,  40, 20, 21, 22, 23);
        AG4(pz,  48, 24, 25, 26, 27); AG4(pz,  56, 28, 29, 30, 31);
        AG4(pz,  64, 32, 33, 34, 35); AG4(pz,  72, 36, 37, 38, 39);
        AG4(pz,  80, 40, 41, 42, 43); AG4(pz,  88, 44, 45, 46, 47);
        AG4(pz,  96, 48, 49, 50, 51); AG4(pz, 104, 52, 53, 54, 55);
        AG4(pz, 112, 56, 57, 58, 59); AG4(pz, 120, 60, 61, 62, 63);
        const _Float16* pr = whT + (size_t)(col + 256) * 256 + k0;
        AG4(pr,   0, 64, 65, 66, 67);   AG4(pr,   8, 68, 69, 70, 71);
        AG4(pr,  16, 72, 73, 74, 75);   AG4(pr,  24, 76, 77, 78, 79);
        AG4(pr,  32, 80, 81, 82, 83);   AG4(pr,  40, 84, 85, 86, 87);
        AG4(pr,  48, 88, 89, 90, 91);   AG4(pr,  56, 92, 93, 94, 95);
        AG4(pr,  64, 96, 97, 98, 99);   AG4(pr,  72, 100, 101, 102, 103);
        AG4(pr,  80, 104, 105, 106, 107); AG4(pr,  88, 108, 109, 110, 111);
        AG4(pr,  96, 112, 113, 114, 115); AG4(pr, 104, 116, 117, 118, 119);
        AG4(pr, 112, 120, 121, 122, 123); AG4(pr, 120, 124, 125, 126, 127);
    }

    if (tid < 256) { hf[tid] = 0.f; hh[tid] = (_Float16)0.f; }
    __syncthreads();

    const f16x8* hh8 = (const f16x8*)hh;    // 32 x 16B, broadcast reads
    const f16x8* rh8 = (const f16x8*)rhh;
    const _Float16* wcb = &wcs[col * 264 + kc * 128];
    float* outb = out + (size_t)b * 32 * 256;

    const float* xrow0 = xg + (size_t)(b * 32) * 768;
    float xz = xrow0[col], xr = xrow0[col + 256], xh = xrow0[col + 512];

    for (int t = 0; t < 32; ++t) {
        const int tn = (t < 31) ? t + 1 : 31;
        const float* xnext = xg + (size_t)(b * 32 + tn) * 768;
        float nxz = xnext[col], nxr = xnext[col + 256], nxh = xnext[col + 512];

        float az0 = 0.f, az1 = 0.f, ar0 = 0.f, ar1 = 0.f;
        ZR(0,   0,  1,  2,  3,  64,  65,  66,  67);
        ZR(1,   4,  5,  6,  7,  68,  69,  70,  71);
        ZR(2,   8,  9, 10, 11,  72,  73,  74,  75);
        ZR(3,  12, 13, 14, 15,  76,  77,  78,  79);
        ZR(4,  16, 17, 18, 19,  80,  81,  82,  83);
        ZR(5,  20, 21, 22, 23,  84,  85,  86,  87);
        ZR(6,  24, 25, 26, 27,  88,  89,  90,  91);
        ZR(7,  28, 29, 30, 31,  92,  93,  94,  95);
        ZR(8,  32, 33, 34, 35,  96,  97,  98,  99);
        ZR(9,  36, 37, 38, 39, 100, 101, 102, 103);
        ZR(10, 40, 41, 42, 43, 104, 105, 106, 107);
        ZR(11, 44, 45, 46, 47, 108, 109, 110, 111);
        ZR(12, 48, 49, 50, 51, 112, 113, 114, 115);
        ZR(13, 52, 53, 54, 55, 116, 117, 118, 119);
        ZR(14, 56, 57, 58, 59, 120, 121, 122, 123);
        ZR(15, 60, 61, 62, 63, 124, 125, 126, 127);

        float azs = az0 + az1;
        float ars = ar0 + ar1;
        azs += __shfl_xor(azs, 32, 64);
        ars += __shfl_xor(ars, 32, 64);
        float hold = hf[col];
        float z = 1.f / (1.f + __expf(-(azs + xz)));
        float r = 1.f / (1.f + __expf(-(ars + xr)));
        if (kc == 0) rhh[col] = (_Float16)(r * hold);
        __syncthreads();                          // B2: rhh visible

        float ah0 = 0.f, ah1 = 0.f;
        CC(0);  CC(1);  CC(2);  CC(3);
        CC(4);  CC(5);  CC(6);  CC(7);
        CC(8);  CC(9);  CC(10); CC(11);
        CC(12); CC(13); CC(14); CC(15);

        float ahs = ah0 + ah1;
        ahs += __shfl_xor(ahs, 32, 64);
        float sx = ahs + xh;
        sx = fminf(fmaxf(sx, -15.f), 15.f);
        float e2 = __expf(2.f * sx);
        float hc = (e2 - 1.f) / (e2 + 1.f);       // tanh
        float hn = z * hold + (1.f - z) * hc;

        if (kc == 0) {
            hf[col] = hn;
            hh[col] = (_Float16)hn;
            outb[t * 256 + col] = hn;
            if (t == 31) out[16 * 32 * 256 + b * 256 + col] = hn;
        }
        xz = nxz; xr = nxr; xh = nxh;
        __syncthreads();                          // B3: h(t) visible
    }
}

// ---------------------------------------------------------------------------
extern "C" void kernel_launch(void* const* d_in, const int* in_sizes, int n_in,
                              void* d_out, int out_size, void* d_ws,
                              size_t ws_size, hipStream_t stream)
{
    const float* x  = (const float*)d_in[0];
    const float* w1 = (const float*)d_in[1];
    const float* b1 = (const float*)d_in[2];
    const float* w2 = (const float*)d_in[3];
    const float* b2 = (const float*)d_in[4];
    const float* dw = (const float*)d_in[5];
    const float* db = (const float*)d_in[6];
    const float* wx = (const float*)d_in[7];
    const float* wh = (const float*)d_in[8];
    const float* bg = (const float*)d_in[9];
    float* out = (float*)d_out;

    float* pooled = (float*)d_ws;                  // 512*64 f32
    float* xg = pooled + 512 * 64;                 // 512*768 f32
    f16x8* w2f = (f16x8*)(xg + 512 * 768);         // 9*4*64 f16x8 (36.9 KB)
    _Float16* whT = (_Float16*)(w2f + 9 * 4 * 64); // 768*256 f16 (384 KB)

    k_prep<<<777, 256, 0, stream>>>(w2, w2f, wh, whT);
    k_conv<<<512, 512, 0, stream>>>(x, w1, b1, w2f, b2, pooled);
    k_dense<<<128, 256, 0, stream>>>(pooled, dw, db, wx, bg, xg);
    k_gru<<<16, 512, 0, stream>>>(whT, xg, out);
}